// Round 1
// baseline (4458.800 us; speedup 1.0000x reference)
//
#include <hip/hip_runtime.h>

// ---------------- problem constants ----------------
#define NN     4096
#define NE     131072
#define IN_CH  512
#define E_CH   64
#define HID    256
#define OUT_CH 16
#define KK     2
#define JJ     3
#define NB     5                      // K + J
#define REWEIGHT 0.6454972243679028f  // sqrt((64+256)/(512+256))

// output element offsets (fp32, concatenated in return order)
#define O_ADJ  0L
#define O_MU   50331648L
#define O_SG   50659328L
#define O_Z    50987008L
#define O_ZS   51183616L
#define O_EPS  51380224L
#define O_RK   51576832L
#define O_SNR  51576848L

// ---------------- kernels ----------------

__global__ void k_deg(const int* __restrict__ dst, float* __restrict__ deg) {
    int i = blockIdx.x * 256 + threadIdx.x;
    if (i < NE) atomicAdd(&deg[dst[i]], 1.0f);
}

__global__ void k_dinv(float* __restrict__ deg) {
    int i = blockIdx.x * 256 + threadIdx.x;
    if (i < NN) deg[i] = rsqrtf(deg[i] + 1.0f);
}

// h_x = x @ W1   (one block per node; 256 threads = 256 out channels)
__global__ void k_gemm_x(const float* __restrict__ x, const float* __restrict__ W1,
                         float* __restrict__ h) {
    __shared__ float row[IN_CH];
    int n = blockIdx.x;
    int c = threadIdx.x;
    for (int k = c; k < IN_CH; k += 256) row[k] = x[n * IN_CH + k];
    __syncthreads();
    float acc = 0.f;
#pragma unroll 8
    for (int k = 0; k < IN_CH; ++k) acc = fmaf(row[k], W1[k * HID + c], acc);
    h[(long)n * HID + c] = acc;
}

// h_e = (e_noise * REWEIGHT) @ We   (one block per (b,n) row)
__global__ void k_gemm_e(const float* __restrict__ e, const float* __restrict__ We,
                         float* __restrict__ h) {
    __shared__ float row[E_CH];
    long bn = blockIdx.x;
    int c = threadIdx.x;
    if (c < E_CH) row[c] = e[bn * E_CH + c] * REWEIGHT;
    __syncthreads();
    float acc = 0.f;
#pragma unroll
    for (int k = 0; k < E_CH; ++k) acc = fmaf(row[k], We[k * HID + c], acc);
    h[bn * HID + c] = acc;
}

// scatter-add aggregation, 256 channels, nb batches.
// thread t -> (b, edge, 4-channel quad)
__global__ void k_agg256(const int* __restrict__ src, const int* __restrict__ dst,
                         const float* __restrict__ dinv, const float* __restrict__ h,
                         float* __restrict__ agg, int nb) {
    long t = (long)blockIdx.x * 256 + threadIdx.x;
    int q = (int)(t & 63);
    long eb = t >> 6;
    int e = (int)(eb % NE);
    int b = (int)(eb / NE);
    if (b >= nb) return;
    int s = src[e], d = dst[e];
    float norm = dinv[s] * dinv[d];
    const float4 v = *reinterpret_cast<const float4*>(&h[((long)b * NN + s) * HID + q * 4]);
    float* out = &agg[((long)b * NN + d) * HID + q * 4];
    atomicAdd(out + 0, v.x * norm);
    atomicAdd(out + 1, v.y * norm);
    atomicAdd(out + 2, v.z * norm);
    atomicAdd(out + 3, v.w * norm);
}

// hidden_x = relu(agg + h*dinv^2 + b1); accumulate sum(hidden_x^2) into psum[0]
__global__ void k_fin_x(const float* __restrict__ h, const float* __restrict__ b1,
                        const float* __restrict__ dinv, float* __restrict__ hx,
                        float* __restrict__ psum) {
    int i = blockIdx.x * 256 + threadIdx.x;   // N*HID
    int n = i / HID, c = i % HID;
    float dv = dinv[n];
    float v = hx[i] + h[i] * dv * dv + b1[c];
    v = fmaxf(v, 0.f);
    hx[i] = v;
    float sq = v * v;
    __shared__ float red[4];
#pragma unroll
    for (int off = 32; off > 0; off >>= 1) sq += __shfl_down(sq, off, 64);
    if ((threadIdx.x & 63) == 0) red[threadIdx.x >> 6] = sq;
    __syncthreads();
    if (threadIdx.x == 0) atomicAdd(&psum[0], red[0] + red[1] + red[2] + red[3]);
}

// hidden_e = agg + h*dinv^2 + be; accumulate per-batch sum(hidden_e^2) into psum[1+b]
__global__ void k_fin_e(const float* __restrict__ h, const float* __restrict__ be,
                        const float* __restrict__ dinv, float* __restrict__ he,
                        float* __restrict__ psum) {
    long i = (long)blockIdx.x * 256 + threadIdx.x;   // NB*N*HID
    int c = (int)(i % HID);
    int n = (int)((i / HID) % NN);
    int b = (int)(i / ((long)NN * HID));
    float dv = dinv[n];
    float v = he[i] + h[i] * dv * dv + be[c];
    he[i] = v;
    float sq = v * v;
    __shared__ float red[4];
#pragma unroll
    for (int off = 32; off > 0; off >>= 1) sq += __shfl_down(sq, off, 64);
    if ((threadIdx.x & 63) == 0) red[threadIdx.x >> 6] = sq;
    __syncthreads();
    if (threadIdx.x == 0) atomicAdd(&psum[1 + b], red[0] + red[1] + red[2] + red[3]);
}

// h_mu / h_sig = (hidden_x + hidden_e) @ {Wmu, Wsig}
// block 256 = 16 rows x 16 out-ch; grid (N/16, NB)
__global__ void k_gemm_ms(const float* __restrict__ hx, const float* __restrict__ he,
                          const float* __restrict__ Wmu, const float* __restrict__ Wsg,
                          float* __restrict__ hmu, float* __restrict__ hsg) {
    int o = threadIdx.x & 15;
    int nn = threadIdx.x >> 4;
    int n = blockIdx.x * 16 + nn;
    int b = blockIdx.y;
    const float* px = &hx[(long)n * HID];
    const float* pe = &he[((long)b * NN + n) * HID];
    float amu = 0.f, asg = 0.f;
#pragma unroll 4
    for (int k = 0; k < HID; ++k) {
        float h1 = px[k] + pe[k];
        amu = fmaf(h1, Wmu[k * OUT_CH + o], amu);
        asg = fmaf(h1, Wsg[k * OUT_CH + o], asg);
    }
    long idx = ((long)b * NN + n) * OUT_CH + o;
    hmu[idx] = amu;
    hsg[idx] = asg;
}

// scatter-add for 16-channel layers (mu and sigma together); thread per (b,edge)
__global__ void k_agg16(const int* __restrict__ src, const int* __restrict__ dst,
                        const float* __restrict__ dinv,
                        const float* __restrict__ hmu, const float* __restrict__ hsg,
                        float* __restrict__ omu, float* __restrict__ osg) {
    long t = (long)blockIdx.x * 256 + threadIdx.x;   // NB*NE
    int e = (int)(t % NE);
    int b = (int)(t / NE);
    if (b >= NB) return;
    int s = src[e], d = dst[e];
    float norm = dinv[s] * dinv[d];
    const float* pm = &hmu[((long)b * NN + s) * OUT_CH];
    float* om = &omu[((long)b * NN + d) * OUT_CH];
#pragma unroll
    for (int c = 0; c < OUT_CH; ++c) atomicAdd(&om[c], pm[c] * norm);
    const float* ps = &hsg[((long)b * NN + s) * OUT_CH];
    float* os = &osg[((long)b * NN + d) * OUT_CH];
#pragma unroll
    for (int c = 0; c < OUT_CH; ++c) atomicAdd(&os[c], ps[c] * norm);
}

__global__ void k_fin_ms(const float* __restrict__ hmu, const float* __restrict__ hsg,
                         const float* __restrict__ bmu, const float* __restrict__ bsg,
                         const float* __restrict__ dinv,
                         float* __restrict__ omu, float* __restrict__ osg) {
    long i = (long)blockIdx.x * 256 + threadIdx.x;   // NB*N*OUT
    int c = (int)(i % OUT_CH);
    int n = (int)((i / OUT_CH) % NN);
    float dv = dinv[n];
    float d2 = dv * dv;
    omu[i] += hmu[i] * d2 + bmu[c];
    osg[i] += hsg[i] * d2 + bsg[c];
}

__global__ void k_z(const float* __restrict__ omu, const float* __restrict__ osg,
                    const float* __restrict__ eps,
                    float* __restrict__ oz, float* __restrict__ ozs, float* __restrict__ oeps) {
    long i = (long)blockIdx.x * 256 + threadIdx.x;   // JJ*N*OUT
    float mu = omu[(long)KK * NN * OUT_CH + i];
    float lv = osg[(long)KK * NN * OUT_CH + i];
    float ep = eps[i];
    float z = fmaf(ep, expf(0.5f * lv), mu);
    oz[i] = z;
    ozs[i] = z;
    oeps[i] = ep;
}

__global__ void k_tail(const float* __restrict__ rk_lgt, const float* __restrict__ psum,
                       float* __restrict__ ork, float* __restrict__ osnr) {
    int t = threadIdx.x;
    if (t < 16) ork[t] = sqrtf(1.f / (1.f + expf(-rk_lgt[t])));
    if (t >= 16 && t < 16 + NB) osnr[t - 16] = psum[0] / psum[1 + (t - 16)];
}

// adj = sigmoid(z @ z^T): 64x64 tile per block, 4x4 micro-tile per thread
__global__ void k_adj(const float* __restrict__ z, float* __restrict__ adj) {
    __shared__ float za[64][17];
    __shared__ float zb[64][17];
    int b  = blockIdx.z;
    int bi = blockIdx.y;
    int bj = blockIdx.x;
    const float* zbase = &z[(long)b * NN * OUT_CH];
    int tid = threadIdx.x;
    for (int l = tid; l < 64 * 16; l += 256) {
        int r = l >> 4, c = l & 15;
        za[r][c] = zbase[((long)bi * 64 + r) * OUT_CH + c];
        zb[r][c] = zbase[((long)bj * 64 + r) * OUT_CH + c];
    }
    __syncthreads();
    int tr = tid >> 4, tc = tid & 15;
    float acc[4][4] = {};
#pragma unroll
    for (int d = 0; d < OUT_CH; ++d) {
        float av[4], bv[4];
#pragma unroll
        for (int i = 0; i < 4; ++i) av[i] = za[tr * 4 + i][d];
#pragma unroll
        for (int j = 0; j < 4; ++j) bv[j] = zb[tc * 4 + j][d];
#pragma unroll
        for (int i = 0; i < 4; ++i)
#pragma unroll
            for (int j = 0; j < 4; ++j) acc[i][j] = fmaf(av[i], bv[j], acc[i][j]);
    }
#pragma unroll
    for (int i = 0; i < 4; ++i) {
        long row = (long)bi * 64 + tr * 4 + i;
        float4 o;
        o.x = 1.f / (1.f + expf(-acc[i][0]));
        o.y = 1.f / (1.f + expf(-acc[i][1]));
        o.z = 1.f / (1.f + expf(-acc[i][2]));
        o.w = 1.f / (1.f + expf(-acc[i][3]));
        *reinterpret_cast<float4*>(&adj[((long)b * NN + row) * NN + (long)bj * 64 + tc * 4]) = o;
    }
}

// ---------------- launch ----------------

extern "C" void kernel_launch(void* const* d_in, const int* in_sizes, int n_in,
                              void* d_out, int out_size, void* d_ws, size_t ws_size,
                              hipStream_t stream) {
    const float* x      = (const float*)d_in[0];
    const int*   eidx   = (const int*)d_in[1];
    const float* enoise = (const float*)d_in[2];
    const float* eps    = (const float*)d_in[3];
    const float* W1     = (const float*)d_in[4];
    const float* b1     = (const float*)d_in[5];
    const float* We     = (const float*)d_in[6];
    const float* be     = (const float*)d_in[7];
    const float* Wmu    = (const float*)d_in[8];
    const float* bmu    = (const float*)d_in[9];
    const float* Wsg    = (const float*)d_in[10];
    const float* bsg    = (const float*)d_in[11];
    const float* rk_lgt = (const float*)d_in[12];

    const int* src = eidx;
    const int* dst = eidx + NE;

    float* out = (float*)d_out;
    float* ws  = (float*)d_ws;

    // workspace layout (floats)
    float* dinv = ws;                          // 4096 (also deg accumulator)
    float* psum = ws + 4096;                   // 16
    float* h_x  = psum + 16;                   // N*HID      = 1048576
    float* hx   = h_x + (long)NN * HID;        // N*HID      (agg -> hidden_x)
    float* h_e  = hx + (long)NN * HID;         // NB*N*HID   = 5242880
    float* he   = h_e + (long)NB * NN * HID;   // NB*N*HID   (agg -> hidden_e)
    float* h_mu = he + (long)NB * NN * HID;    // NB*N*OUT   = 327680
    float* h_sg = h_mu + (long)NB * NN * OUT_CH;

    float* omu  = out + O_MU;
    float* osg  = out + O_SG;

    // zero accumulators
    hipMemsetAsync(dinv, 0, NN * sizeof(float), stream);
    hipMemsetAsync(psum, 0, 16 * sizeof(float), stream);
    hipMemsetAsync(hx, 0, (long)NN * HID * sizeof(float), stream);
    hipMemsetAsync(he, 0, (long)NB * NN * HID * sizeof(float), stream);
    hipMemsetAsync(omu, 0, (long)NB * NN * OUT_CH * sizeof(float), stream);
    hipMemsetAsync(osg, 0, (long)NB * NN * OUT_CH * sizeof(float), stream);

    k_deg<<<NE / 256, 256, 0, stream>>>(dst, dinv);
    k_dinv<<<NN / 256, 256, 0, stream>>>(dinv);

    k_gemm_x<<<NN, 256, 0, stream>>>(x, W1, h_x);
    k_gemm_e<<<NB * NN, 256, 0, stream>>>(enoise, We, h_e);

    k_agg256<<<1 * (NE * 64 / 256), 256, 0, stream>>>(src, dst, dinv, h_x, hx, 1);
    k_fin_x<<<NN * HID / 256, 256, 0, stream>>>(h_x, b1, dinv, hx, psum);

    k_agg256<<<NB * (NE * 64 / 256), 256, 0, stream>>>(src, dst, dinv, h_e, he, NB);
    k_fin_e<<<NB * NN * HID / 256, 256, 0, stream>>>(h_e, be, dinv, he, psum);

    k_gemm_ms<<<dim3(NN / 16, NB), 256, 0, stream>>>(hx, he, Wmu, Wsg, h_mu, h_sg);
    k_agg16<<<NB * NE / 256, 256, 0, stream>>>(src, dst, dinv, h_mu, h_sg, omu, osg);
    k_fin_ms<<<NB * NN * OUT_CH / 256, 256, 0, stream>>>(h_mu, h_sg, bmu, bsg, dinv, omu, osg);

    k_z<<<(long)JJ * NN * OUT_CH / 256, 256, 0, stream>>>(omu, osg, eps,
                                                          out + O_Z, out + O_ZS, out + O_EPS);
    k_tail<<<1, 64, 0, stream>>>(rk_lgt, psum, out + O_RK, out + O_SNR);

    k_adj<<<dim3(NN / 64, NN / 64, JJ), 256, 0, stream>>>(out + O_Z, out);
}

// Round 2
// 549.931 us; speedup vs baseline: 8.1079x; 8.1079x over previous
//
#include <hip/hip_runtime.h>

// ---------------- problem constants ----------------
#define NN     4096
#define NE     131072
#define IN_CH  512
#define E_CH   64
#define HID    256
#define OUT_CH 16
#define KK     2
#define JJ     3
#define NB     5                      // K + J
#define REWEIGHT 0.6454972243679028f  // sqrt((64+256)/(512+256))

// output element offsets (fp32, concatenated in return order)
#define O_ADJ  0L
#define O_MU   50331648L
#define O_SG   50659328L
#define O_Z    50987008L
#define O_ZS   51183616L
#define O_EPS  51380224L
#define O_RK   51576832L
#define O_SNR  51576848L

// ---------------- CSR build ----------------

__global__ void k_deg(const int* __restrict__ dst, int* __restrict__ degi) {
    int i = blockIdx.x * 256 + threadIdx.x;
    if (i < NE) atomicAdd(&degi[dst[i]], 1);
}

// single block, 1024 threads: exclusive scan of degi[4096] -> rowptr[4097], cursor copy
__global__ void k_scan(const int* __restrict__ degi, int* __restrict__ rowptr,
                       int* __restrict__ cursor) {
    __shared__ int sums[1024];
    int t = threadIdx.x;
    int v[4];
    int s = 0;
#pragma unroll
    for (int i = 0; i < 4; ++i) { v[i] = s; s += degi[t * 4 + i]; }
    sums[t] = s;
    __syncthreads();
    for (int off = 1; off < 1024; off <<= 1) {
        int a = (t >= off) ? sums[t - off] : 0;
        __syncthreads();
        sums[t] += a;
        __syncthreads();
    }
    int base = (t > 0) ? sums[t - 1] : 0;
#pragma unroll
    for (int i = 0; i < 4; ++i) {
        rowptr[t * 4 + i] = base + v[i];
        cursor[t * 4 + i] = base + v[i];
    }
    if (t == 1023) rowptr[4096] = sums[1023];
}

__global__ void k_dinv(const int* __restrict__ degi, float* __restrict__ dinv) {
    int i = blockIdx.x * 256 + threadIdx.x;
    if (i < NN) dinv[i] = rsqrtf((float)degi[i] + 1.0f);
}

// scatter edges into dst-sorted order; store src idx and precomputed norm
__global__ void k_fill(const int* __restrict__ src, const int* __restrict__ dst,
                       const float* __restrict__ dinv,
                       int* __restrict__ cursor, int* __restrict__ esrc,
                       float* __restrict__ enorm) {
    int i = blockIdx.x * 256 + threadIdx.x;
    if (i >= NE) return;
    int s = src[i], d = dst[i];
    int pos = atomicAdd(&cursor[d], 1);
    esrc[pos] = s;
    enorm[pos] = dinv[s] * dinv[d];
}

// ---------------- GEMMs ----------------

// h_x = x @ W1 : block = 256 out channels, 4 node rows
__global__ void k_gemm_x(const float* __restrict__ x, const float* __restrict__ W1,
                         float* __restrict__ h) {
    __shared__ float xs[4][IN_CH];
    long r0 = (long)blockIdx.x * 4;
    int c = threadIdx.x;
    for (int idx = c; idx < 4 * IN_CH; idx += 256) {
        int rr = idx >> 9, k = idx & 511;
        xs[rr][k] = x[(r0 + rr) * IN_CH + k];
    }
    __syncthreads();
    float acc[4] = {};
#pragma unroll 4
    for (int k = 0; k < IN_CH; ++k) {
        float w = W1[k * HID + c];
#pragma unroll
        for (int rr = 0; rr < 4; ++rr) acc[rr] = fmaf(xs[rr][k], w, acc[rr]);
    }
#pragma unroll
    for (int rr = 0; rr < 4; ++rr) h[(r0 + rr) * HID + c] = acc[rr];
}

// pre-aggregate e on 64 channels: u[b,n,:] = REWEIGHT*(e[b,n]*dinv^2 + sum norm*e[b,src])
__global__ void __launch_bounds__(64) k_agg_e(const float* __restrict__ e,
                        const int* __restrict__ rowptr, const int* __restrict__ esrc,
                        const float* __restrict__ enorm, const float* __restrict__ dinv,
                        float* __restrict__ u) {
    int n = blockIdx.x, b = blockIdx.y;
    int c = threadIdx.x;
    int beg = rowptr[n], end = rowptr[n + 1];
    float dv = dinv[n];
    const float* eb = &e[(long)b * NN * E_CH];
    float acc = eb[(long)n * E_CH + c] * dv * dv;
    for (int j = beg; j < end; ++j)
        acc = fmaf(eb[(long)esrc[j] * E_CH + c], enorm[j], acc);
    u[((long)b * NN + n) * E_CH + c] = acc * REWEIGHT;
}

// hidden_e = u @ We + be, with per-batch sum-of-squares into psum[1+b]
// block = 256 out channels, 8 rows; 512 blocks per batch
__global__ void k_gemm_e(const float* __restrict__ u, const float* __restrict__ We,
                         const float* __restrict__ be, float* __restrict__ he,
                         float* __restrict__ psum) {
    __shared__ float us[8][E_CH];
    long r0 = (long)blockIdx.x * 8;
    int c = threadIdx.x;
    for (int idx = c; idx < 8 * E_CH; idx += 256) {
        int rr = idx >> 6, k = idx & 63;
        us[rr][k] = u[(r0 + rr) * E_CH + k];
    }
    __syncthreads();
    float acc[8] = {};
#pragma unroll
    for (int k = 0; k < E_CH; ++k) {
        float w = We[k * HID + c];
#pragma unroll
        for (int rr = 0; rr < 8; ++rr) acc[rr] = fmaf(us[rr][k], w, acc[rr]);
    }
    float bias = be[c];
    float sq = 0.f;
#pragma unroll
    for (int rr = 0; rr < 8; ++rr) {
        float v = acc[rr] + bias;
        he[(r0 + rr) * HID + c] = v;
        sq += v * v;
    }
#pragma unroll
    for (int off = 32; off; off >>= 1) sq += __shfl_down(sq, off, 64);
    __shared__ float red[4];
    if ((threadIdx.x & 63) == 0) red[threadIdx.x >> 6] = sq;
    __syncthreads();
    if (threadIdx.x == 0) {
        int b = blockIdx.x >> 9;   // 512 blocks per batch
        atomicAdd(&psum[1 + b], red[0] + red[1] + red[2] + red[3]);
    }
}

// hidden_x = relu(gather + self + b1); accumulate sum(hidden_x^2)
__global__ void k_agg_x(const float* __restrict__ h, const int* __restrict__ rowptr,
                        const int* __restrict__ esrc, const float* __restrict__ enorm,
                        const float* __restrict__ dinv, const float* __restrict__ b1,
                        float* __restrict__ hx, float* __restrict__ psum) {
    int n = blockIdx.x;
    int c = threadIdx.x;
    int beg = rowptr[n], end = rowptr[n + 1];
    float dv = dinv[n];
    float acc = h[(long)n * HID + c] * dv * dv + b1[c];
    for (int j = beg; j < end; ++j)
        acc = fmaf(h[(long)esrc[j] * HID + c], enorm[j], acc);
    acc = fmaxf(acc, 0.f);
    hx[(long)n * HID + c] = acc;
    float sq = acc * acc;
#pragma unroll
    for (int off = 32; off; off >>= 1) sq += __shfl_down(sq, off, 64);
    __shared__ float red[4];
    if ((threadIdx.x & 63) == 0) red[threadIdx.x >> 6] = sq;
    __syncthreads();
    if (threadIdx.x == 0) atomicAdd(&psum[0], red[0] + red[1] + red[2] + red[3]);
}

// h_mu / h_sig = (hidden_x + hidden_e) @ {Wmu, Wsig}
__global__ void k_gemm_ms(const float* __restrict__ hx, const float* __restrict__ he,
                          const float* __restrict__ Wmu, const float* __restrict__ Wsg,
                          float* __restrict__ hmu, float* __restrict__ hsg) {
    int o = threadIdx.x & 15;
    int nn = threadIdx.x >> 4;
    int n = blockIdx.x * 16 + nn;
    int b = blockIdx.y;
    const float* px = &hx[(long)n * HID];
    const float* pe = &he[((long)b * NN + n) * HID];
    float amu = 0.f, asg = 0.f;
#pragma unroll 4
    for (int k = 0; k < HID; ++k) {
        float h1 = px[k] + pe[k];
        amu = fmaf(h1, Wmu[k * OUT_CH + o], amu);
        asg = fmaf(h1, Wsg[k * OUT_CH + o], asg);
    }
    long idx = ((long)b * NN + n) * OUT_CH + o;
    hmu[idx] = amu;
    hsg[idx] = asg;
}

// gather-aggregate 16-channel mu/sigma (incl. self + bias) -> final mu, sigma
// block 256 = 16 edge-slots x 16 channels
__global__ void k_agg16(const int* __restrict__ rowptr, const int* __restrict__ esrc,
                        const float* __restrict__ enorm, const float* __restrict__ dinv,
                        const float* __restrict__ hmu, const float* __restrict__ hsg,
                        const float* __restrict__ bmu, const float* __restrict__ bsg,
                        float* __restrict__ omu, float* __restrict__ osg) {
    int n = blockIdx.x, b = blockIdx.y;
    int t = threadIdx.x;
    int es = t >> 4, c = t & 15;
    int beg = rowptr[n], end = rowptr[n + 1];
    const float* pm = &hmu[(long)b * NN * OUT_CH];
    const float* ps = &hsg[(long)b * NN * OUT_CH];
    float am = 0.f, as = 0.f;
    for (int j = beg + es; j < end; j += 16) {
        int s = esrc[j];
        float w = enorm[j];
        am = fmaf(pm[(long)s * OUT_CH + c], w, am);
        as = fmaf(ps[(long)s * OUT_CH + c], w, as);
    }
    // reduce the 4 edge-slots within each wave
    am += __shfl_xor(am, 16, 64); as += __shfl_xor(as, 16, 64);
    am += __shfl_xor(am, 32, 64); as += __shfl_xor(as, 32, 64);
    __shared__ float rm[4][16], rs[4][16];
    int w = t >> 6;
    if ((t & 63) < 16) { rm[w][t & 15] = am; rs[w][t & 15] = as; }
    __syncthreads();
    float dv = dinv[n];
    float d2 = dv * dv;
    long base = ((long)b * NN + n) * OUT_CH;
    if (t < 16) {
        float v = rm[0][t] + rm[1][t] + rm[2][t] + rm[3][t]
                + pm[(long)n * OUT_CH + t] * d2 + bmu[t];
        omu[base + t] = v;
    } else if (t < 32) {
        int c2 = t - 16;
        float v = rs[0][c2] + rs[1][c2] + rs[2][c2] + rs[3][c2]
                + ps[(long)n * OUT_CH + c2] * d2 + bsg[c2];
        osg[base + c2] = v;
    }
}

// ---------------- tail ----------------

__global__ void k_z(const float* __restrict__ omu, const float* __restrict__ osg,
                    const float* __restrict__ eps,
                    float* __restrict__ oz, float* __restrict__ ozs, float* __restrict__ oeps) {
    long i = (long)blockIdx.x * 256 + threadIdx.x;   // JJ*N*OUT
    float mu = omu[(long)KK * NN * OUT_CH + i];
    float lv = osg[(long)KK * NN * OUT_CH + i];
    float ep = eps[i];
    float z = fmaf(ep, expf(0.5f * lv), mu);
    oz[i] = z;
    ozs[i] = z;
    oeps[i] = ep;
}

__global__ void k_tail(const float* __restrict__ rk_lgt, const float* __restrict__ psum,
                       float* __restrict__ ork, float* __restrict__ osnr) {
    int t = threadIdx.x;
    if (t < 16) ork[t] = sqrtf(1.f / (1.f + expf(-rk_lgt[t])));
    if (t >= 16 && t < 16 + NB) osnr[t - 16] = psum[0] / psum[1 + (t - 16)];
}

// adj = sigmoid(z @ z^T): 64x64 tile per block, 4x4 micro-tile per thread
__global__ void k_adj(const float* __restrict__ z, float* __restrict__ adj) {
    __shared__ float za[64][17];
    __shared__ float zb[64][17];
    int b  = blockIdx.z;
    int bi = blockIdx.y;
    int bj = blockIdx.x;
    const float* zbase = &z[(long)b * NN * OUT_CH];
    int tid = threadIdx.x;
    for (int l = tid; l < 64 * 16; l += 256) {
        int r = l >> 4, c = l & 15;
        za[r][c] = zbase[((long)bi * 64 + r) * OUT_CH + c];
        zb[r][c] = zbase[((long)bj * 64 + r) * OUT_CH + c];
    }
    __syncthreads();
    int tr = tid >> 4, tc = tid & 15;
    float acc[4][4] = {};
#pragma unroll
    for (int d = 0; d < OUT_CH; ++d) {
        float av[4], bv[4];
#pragma unroll
        for (int i = 0; i < 4; ++i) av[i] = za[tr * 4 + i][d];
#pragma unroll
        for (int j = 0; j < 4; ++j) bv[j] = zb[tc * 4 + j][d];
#pragma unroll
        for (int i = 0; i < 4; ++i)
#pragma unroll
            for (int j = 0; j < 4; ++j) acc[i][j] = fmaf(av[i], bv[j], acc[i][j]);
    }
#pragma unroll
    for (int i = 0; i < 4; ++i) {
        long row = (long)bi * 64 + tr * 4 + i;
        float4 o;
        o.x = 1.f / (1.f + expf(-acc[i][0]));
        o.y = 1.f / (1.f + expf(-acc[i][1]));
        o.z = 1.f / (1.f + expf(-acc[i][2]));
        o.w = 1.f / (1.f + expf(-acc[i][3]));
        *reinterpret_cast<float4*>(&adj[((long)b * NN + row) * NN + (long)bj * 64 + tc * 4]) = o;
    }
}

// ---------------- launch ----------------

extern "C" void kernel_launch(void* const* d_in, const int* in_sizes, int n_in,
                              void* d_out, int out_size, void* d_ws, size_t ws_size,
                              hipStream_t stream) {
    const float* x      = (const float*)d_in[0];
    const int*   eidx   = (const int*)d_in[1];
    const float* enoise = (const float*)d_in[2];
    const float* eps    = (const float*)d_in[3];
    const float* W1     = (const float*)d_in[4];
    const float* b1     = (const float*)d_in[5];
    const float* We     = (const float*)d_in[6];
    const float* be     = (const float*)d_in[7];
    const float* Wmu    = (const float*)d_in[8];
    const float* bmu    = (const float*)d_in[9];
    const float* Wsg    = (const float*)d_in[10];
    const float* bsg    = (const float*)d_in[11];
    const float* rk_lgt = (const float*)d_in[12];

    const int* src = eidx;
    const int* dst = eidx + NE;

    float* out = (float*)d_out;
    char*  ws  = (char*)d_ws;

    // workspace layout
    int*   degi   = (int*)ws;                          // 4096
    int*   rowptr = degi + 4096;                       // 4097
    int*   cursor = rowptr + 4097 + 3;                 // 4096 (pad to 8-align)
    int*   esrc   = cursor + 4096;                     // NE
    float* enorm  = (float*)(esrc + NE);               // NE
    float* dinv   = enorm + NE;                        // 4096
    float* psum   = dinv + 4096;                       // 16
    float* h_x    = psum + 16;                         // N*HID
    float* hx     = h_x + (long)NN * HID;              // N*HID
    float* u_e    = hx + (long)NN * HID;               // NB*N*E_CH
    float* he     = u_e + (long)NB * NN * E_CH;        // NB*N*HID
    float* h_mu   = he + (long)NB * NN * HID;          // NB*N*OUT
    float* h_sg   = h_mu + (long)NB * NN * OUT_CH;     // NB*N*OUT

    float* omu = out + O_MU;
    float* osg = out + O_SG;

    hipMemsetAsync(degi, 0, NN * sizeof(int), stream);
    hipMemsetAsync(psum, 0, 16 * sizeof(float), stream);

    // CSR build
    k_deg<<<NE / 256, 256, 0, stream>>>(dst, degi);
    k_scan<<<1, 1024, 0, stream>>>(degi, rowptr, cursor);
    k_dinv<<<NN / 256, 256, 0, stream>>>(degi, dinv);
    k_fill<<<NE / 256, 256, 0, stream>>>(src, dst, dinv, cursor, esrc, enorm);

    // x branch
    k_gemm_x<<<NN / 4, 256, 0, stream>>>(x, W1, h_x);
    k_agg_x<<<NN, 256, 0, stream>>>(h_x, rowptr, esrc, enorm, dinv, b1, hx, psum);

    // e branch: aggregate on 64 ch, then GEMM (+bias +sumsq)
    k_agg_e<<<dim3(NN, NB), 64, 0, stream>>>(enoise, rowptr, esrc, enorm, dinv, u_e);
    k_gemm_e<<<NB * NN / 8, 256, 0, stream>>>(u_e, We, be, he, psum);

    // mu / sigma
    k_gemm_ms<<<dim3(NN / 16, NB), 256, 0, stream>>>(hx, he, Wmu, Wsg, h_mu, h_sg);
    k_agg16<<<dim3(NN, NB), 256, 0, stream>>>(rowptr, esrc, enorm, dinv,
                                              h_mu, h_sg, bmu, bsg, omu, osg);

    // tail
    k_z<<<(long)JJ * NN * OUT_CH / 256, 256, 0, stream>>>(omu, osg, eps,
                                                          out + O_Z, out + O_ZS, out + O_EPS);
    k_tail<<<1, 64, 0, stream>>>(rk_lgt, psum, out + O_RK, out + O_SNR);

    k_adj<<<dim3(NN / 64, NN / 64, JJ), 256, 0, stream>>>(out + O_Z, out);
}

// Round 6
// 543.321 us; speedup vs baseline: 8.2066x; 1.0122x over previous
//
#include <hip/hip_runtime.h>

// ---------------- problem constants ----------------
#define NN     4096
#define NE     131072
#define IN_CH  512
#define E_CH   64
#define HID    256
#define OUT_CH 16
#define KK     2
#define JJ     3
#define NB     5                      // K + J
#define REWEIGHT 0.6454972243679028f  // sqrt((64+256)/(512+256))

// output element offsets (fp32, concatenated in return order)
#define O_ADJ  0L
#define O_MU   50331648L
#define O_SG   50659328L
#define O_Z    50987008L
#define O_ZS   51183616L
#define O_EPS  51380224L
#define O_RK   51576832L
#define O_SNR  51576848L

__device__ __forceinline__ float fast_sigmoid(float x) {
    float e = __expf(-x);
    return __builtin_amdgcn_rcpf(1.f + e);
}

// ---------------- CSR build ----------------

__global__ void k_deg(const int* __restrict__ dst, int* __restrict__ degi) {
    int i = blockIdx.x * 256 + threadIdx.x;
    if (i < NE) atomicAdd(&degi[dst[i]], 1);
}

// single block, 1024 threads: exclusive scan of degi[4096] -> rowptr[4097] + cursor + dinv
__global__ void __launch_bounds__(1024) k_scan(const int* __restrict__ degi,
                       int* __restrict__ rowptr, int* __restrict__ cursor,
                       float* __restrict__ dinv) {
    __shared__ int sums[1024];
    int t = threadIdx.x;
    int d0[4], v[4];
    int s = 0;
#pragma unroll
    for (int i = 0; i < 4; ++i) { d0[i] = degi[t * 4 + i]; v[i] = s; s += d0[i]; }
    sums[t] = s;
    __syncthreads();
    for (int off = 1; off < 1024; off <<= 1) {
        int a = (t >= off) ? sums[t - off] : 0;
        __syncthreads();
        sums[t] += a;
        __syncthreads();
    }
    int base = (t > 0) ? sums[t - 1] : 0;
#pragma unroll
    for (int i = 0; i < 4; ++i) {
        rowptr[t * 4 + i] = base + v[i];
        cursor[t * 4 + i] = base + v[i];
        dinv[t * 4 + i] = rsqrtf((float)d0[i] + 1.0f);
    }
    if (t == 1023) rowptr[4096] = sums[1023];
}

// scatter edges into dst-sorted order; store src idx and precomputed norm
__global__ void k_fill(const int* __restrict__ src, const int* __restrict__ dst,
                       const float* __restrict__ dinv,
                       int* __restrict__ cursor, int* __restrict__ esrc,
                       float* __restrict__ enorm) {
    int i = blockIdx.x * 256 + threadIdx.x;
    if (i >= NE) return;
    int s = src[i], d = dst[i];
    int pos = atomicAdd(&cursor[d], 1);
    esrc[pos] = s;
    enorm[pos] = dinv[s] * dinv[d];
}

// ---------------- GEMMs ----------------

// h_x = x @ W1 : block = 256 out channels, 8 node rows
__global__ void __launch_bounds__(256) k_gemm_x(const float* __restrict__ x,
                         const float* __restrict__ W1, float* __restrict__ h) {
    __shared__ float xs[8][IN_CH];
    long r0 = (long)blockIdx.x * 8;
    int c = threadIdx.x;
    for (int idx = c; idx < 8 * IN_CH; idx += 256) {
        int rr = idx >> 9, k = idx & 511;
        xs[rr][k] = x[(r0 + rr) * IN_CH + k];
    }
    __syncthreads();
    float acc[8] = {};
#pragma unroll 4
    for (int k = 0; k < IN_CH; ++k) {
        float w = W1[k * HID + c];
#pragma unroll
        for (int rr = 0; rr < 8; ++rr) acc[rr] = fmaf(xs[rr][k], w, acc[rr]);
    }
#pragma unroll
    for (int rr = 0; rr < 8; ++rr) h[(r0 + rr) * HID + c] = acc[rr];
}

// hidden_x = relu(gather + self + b1); accumulate sum(hidden_x^2)
__global__ void __launch_bounds__(256) k_agg_x(const float* __restrict__ h,
                        const int* __restrict__ rowptr,
                        const int* __restrict__ esrc, const float* __restrict__ enorm,
                        const float* __restrict__ dinv, const float* __restrict__ b1,
                        float* __restrict__ hx, float* __restrict__ psum) {
    int n = blockIdx.x;
    int c = threadIdx.x;
    int beg = rowptr[n], end = rowptr[n + 1];
    float dv = dinv[n];
    float acc = h[(long)n * HID + c] * dv * dv + b1[c];
    for (int j = beg; j < end; ++j)
        acc = fmaf(h[(long)esrc[j] * HID + c], enorm[j], acc);
    acc = fmaxf(acc, 0.f);
    hx[(long)n * HID + c] = acc;
    float sq = acc * acc;
#pragma unroll
    for (int off = 32; off; off >>= 1) sq += __shfl_down(sq, off, 64);
    __shared__ float red[4];
    if ((threadIdx.x & 63) == 0) red[threadIdx.x >> 6] = sq;
    __syncthreads();
    if (threadIdx.x == 0) atomicAdd(&psum[0], red[0] + red[1] + red[2] + red[3]);
}

// pre-aggregate e on 64 channels, all NB batches per wave; one wave per node
__global__ void __launch_bounds__(256) k_agg_e(const float* __restrict__ e,
                        const int* __restrict__ rowptr, const int* __restrict__ esrc,
                        const float* __restrict__ enorm, const float* __restrict__ dinv,
                        float* __restrict__ u) {
    int n = blockIdx.x * 4 + (threadIdx.x >> 6);
    int c = threadIdx.x & 63;
    int beg = rowptr[n], end = rowptr[n + 1];
    float dv = dinv[n];
    float d2 = dv * dv;
    float acc[NB];
#pragma unroll
    for (int b = 0; b < NB; ++b) acc[b] = e[((long)b * NN + n) * E_CH + c] * d2;
    for (int j = beg; j < end; ++j) {
        int s = esrc[j];
        float w = enorm[j];
        long base = (long)s * E_CH + c;
#pragma unroll
        for (int b = 0; b < NB; ++b)
            acc[b] = fmaf(e[(long)b * NN * E_CH + base], w, acc[b]);
    }
#pragma unroll
    for (int b = 0; b < NB; ++b) u[((long)b * NN + n) * E_CH + c] = acc[b] * REWEIGHT;
}

// hidden_e = u @ We + be, with per-batch sum-of-squares into psum[1+b]
__global__ void __launch_bounds__(256) k_gemm_e(const float* __restrict__ u,
                         const float* __restrict__ We,
                         const float* __restrict__ be, float* __restrict__ he,
                         float* __restrict__ psum) {
    __shared__ float us[8][E_CH];
    long r0 = (long)blockIdx.x * 8;
    int c = threadIdx.x;
    for (int idx = c; idx < 8 * E_CH; idx += 256) {
        int rr = idx >> 6, k = idx & 63;
        us[rr][k] = u[(r0 + rr) * E_CH + k];
    }
    __syncthreads();
    float acc[8] = {};
#pragma unroll
    for (int k = 0; k < E_CH; ++k) {
        float w = We[k * HID + c];
#pragma unroll
        for (int rr = 0; rr < 8; ++rr) acc[rr] = fmaf(us[rr][k], w, acc[rr]);
    }
    float bias = be[c];
    float sq = 0.f;
#pragma unroll
    for (int rr = 0; rr < 8; ++rr) {
        float v = acc[rr] + bias;
        he[(r0 + rr) * HID + c] = v;
        sq += v * v;
    }
#pragma unroll
    for (int off = 32; off; off >>= 1) sq += __shfl_down(sq, off, 64);
    __shared__ float red[4];
    if ((threadIdx.x & 63) == 0) red[threadIdx.x >> 6] = sq;
    __syncthreads();
    if (threadIdx.x == 0) {
        int b = blockIdx.x >> 9;   // 512 blocks per batch
        atomicAdd(&psum[1 + b], red[0] + red[1] + red[2] + red[3]);
    }
}

// h_mu / h_sig = (hidden_x + hidden_e) @ {Wmu, Wsig}
__global__ void __launch_bounds__(256) k_gemm_ms(const float* __restrict__ hx,
                          const float* __restrict__ he,
                          const float* __restrict__ Wmu, const float* __restrict__ Wsg,
                          float* __restrict__ hmu, float* __restrict__ hsg) {
    int o = threadIdx.x & 15;
    int nn = threadIdx.x >> 4;
    int n = blockIdx.x * 16 + nn;
    int b = blockIdx.y;
    const float* px = &hx[(long)n * HID];
    const float* pe = &he[((long)b * NN + n) * HID];
    float amu = 0.f, asg = 0.f;
#pragma unroll 4
    for (int k = 0; k < HID; ++k) {
        float h1 = px[k] + pe[k];
        amu = fmaf(h1, Wmu[k * OUT_CH + o], amu);
        asg = fmaf(h1, Wsg[k * OUT_CH + o], asg);
    }
    long idx = ((long)b * NN + n) * OUT_CH + o;
    hmu[idx] = amu;
    hsg[idx] = asg;
}

// gather-aggregate 16-ch mu/sigma; one wave per (b,n) pair, 4 pairs per block
__global__ void __launch_bounds__(256) k_agg16(const int* __restrict__ rowptr,
                        const int* __restrict__ esrc,
                        const float* __restrict__ enorm, const float* __restrict__ dinv,
                        const float* __restrict__ hmu, const float* __restrict__ hsg,
                        const float* __restrict__ bmu, const float* __restrict__ bsg,
                        float* __restrict__ omu, float* __restrict__ osg) {
    int p = blockIdx.x * 4 + (threadIdx.x >> 6);    // pair index: b*NN + n
    int lane = threadIdx.x & 63;
    int n = p & (NN - 1);
    int b = p >> 12;
    int es = lane >> 4, c = lane & 15;
    int beg = rowptr[n], end = rowptr[n + 1];
    const float* pm = &hmu[(long)b * NN * OUT_CH];
    const float* ps = &hsg[(long)b * NN * OUT_CH];
    float am = 0.f, as = 0.f;
    for (int j = beg + es; j < end; j += 4) {
        int s = esrc[j];
        float w = enorm[j];
        am = fmaf(pm[(long)s * OUT_CH + c], w, am);
        as = fmaf(ps[(long)s * OUT_CH + c], w, as);
    }
    am += __shfl_xor(am, 16, 64); as += __shfl_xor(as, 16, 64);
    am += __shfl_xor(am, 32, 64); as += __shfl_xor(as, 32, 64);
    float dv = dinv[n];
    float d2 = dv * dv;
    long base = ((long)b * NN + n) * OUT_CH;
    if (lane < 16) {
        omu[base + c] = am + pm[(long)n * OUT_CH + c] * d2 + bmu[c];
    } else if (lane < 32) {
        osg[base + c] = as + ps[(long)n * OUT_CH + c] * d2 + bsg[c];
    }
}

// ---------------- tail ----------------

__global__ void k_z(const float* __restrict__ omu, const float* __restrict__ osg,
                    const float* __restrict__ eps,
                    float* __restrict__ oz, float* __restrict__ ozs, float* __restrict__ oeps,
                    const float* __restrict__ rk_lgt, const float* __restrict__ psum,
                    float* __restrict__ ork, float* __restrict__ osnr) {
    long i = (long)blockIdx.x * 256 + threadIdx.x;   // JJ*N*OUT
    float mu = omu[(long)KK * NN * OUT_CH + i];
    float lv = osg[(long)KK * NN * OUT_CH + i];
    float ep = eps[i];
    float z = fmaf(ep, expf(0.5f * lv), mu);
    oz[i] = z;
    ozs[i] = z;
    oeps[i] = ep;
    if (blockIdx.x == 0) {
        int t = threadIdx.x;
        if (t < 16) ork[t] = sqrtf(1.f / (1.f + expf(-rk_lgt[t])));
        if (t >= 16 && t < 16 + NB) osnr[t - 16] = psum[0] / psum[1 + (t - 16)];
    }
}

// adj = sigmoid(z @ z^T): 128x128 tile per block, 8x8 micro-tile per thread,
// transposed padded LDS so fragments are float4 (ds_read_b128)
__global__ void __launch_bounds__(256) k_adj(const float* __restrict__ z,
                                             float* __restrict__ adj) {
    __shared__ float zaT[16][132];
    __shared__ float zbT[16][132];
    int b  = blockIdx.z;
    int bi = blockIdx.y;
    int bj = blockIdx.x;
    const float* zbase = &z[(long)b * NN * OUT_CH];
    int tid = threadIdx.x;
    for (int l = tid; l < 128 * 16; l += 256) {
        int r = l >> 4, c = l & 15;
        zaT[c][r] = zbase[((long)bi * 128 + r) * OUT_CH + c];
        zbT[c][r] = zbase[((long)bj * 128 + r) * OUT_CH + c];
    }
    __syncthreads();
    int tr = tid >> 4, tc = tid & 15;
    float acc[8][8] = {};
#pragma unroll
    for (int d = 0; d < OUT_CH; ++d) {
        float4 a0 = *reinterpret_cast<const float4*>(&zaT[d][tr * 8]);
        float4 a1 = *reinterpret_cast<const float4*>(&zaT[d][tr * 8 + 4]);
        float4 b0 = *reinterpret_cast<const float4*>(&zbT[d][tc * 8]);
        float4 b1 = *reinterpret_cast<const float4*>(&zbT[d][tc * 8 + 4]);
        float av[8] = {a0.x, a0.y, a0.z, a0.w, a1.x, a1.y, a1.z, a1.w};
        float bv[8] = {b0.x, b0.y, b0.z, b0.w, b1.x, b1.y, b1.z, b1.w};
#pragma unroll
        for (int i = 0; i < 8; ++i)
#pragma unroll
            for (int j = 0; j < 8; ++j) acc[i][j] = fmaf(av[i], bv[j], acc[i][j]);
    }
#pragma unroll
    for (int i = 0; i < 8; ++i) {
        long row = (long)bi * 128 + tr * 8 + i;
        float* orow = &adj[((long)b * NN + row) * NN + (long)bj * 128 + tc * 8];
        float4 o0, o1;
        o0.x = fast_sigmoid(acc[i][0]); o0.y = fast_sigmoid(acc[i][1]);
        o0.z = fast_sigmoid(acc[i][2]); o0.w = fast_sigmoid(acc[i][3]);
        o1.x = fast_sigmoid(acc[i][4]); o1.y = fast_sigmoid(acc[i][5]);
        o1.z = fast_sigmoid(acc[i][6]); o1.w = fast_sigmoid(acc[i][7]);
        *reinterpret_cast<float4*>(&orow[0]) = o0;
        *reinterpret_cast<float4*>(&orow[4]) = o1;
    }
}

// ---------------- launch ----------------

extern "C" void kernel_launch(void* const* d_in, const int* in_sizes, int n_in,
                              void* d_out, int out_size, void* d_ws, size_t ws_size,
                              hipStream_t stream) {
    const float* x      = (const float*)d_in[0];
    const int*   eidx   = (const int*)d_in[1];
    const float* enoise = (const float*)d_in[2];
    const float* eps    = (const float*)d_in[3];
    const float* W1     = (const float*)d_in[4];
    const float* b1     = (const float*)d_in[5];
    const float* We     = (const float*)d_in[6];
    const float* be     = (const float*)d_in[7];
    const float* Wmu    = (const float*)d_in[8];
    const float* bmu    = (const float*)d_in[9];
    const float* Wsg    = (const float*)d_in[10];
    const float* bsg    = (const float*)d_in[11];
    const float* rk_lgt = (const float*)d_in[12];

    const int* src = eidx;
    const int* dst = eidx + NE;

    float* out = (float*)d_out;
    char*  ws  = (char*)d_ws;

    // workspace layout
    int*   degi   = (int*)ws;                          // 4096
    int*   rowptr = degi + 4096;                       // 4097
    int*   cursor = rowptr + 4097 + 3;                 // 4096 (pad to 8-align)
    int*   esrc   = cursor + 4096;                     // NE
    float* enorm  = (float*)(esrc + NE);               // NE
    float* dinv   = enorm + NE;                        // 4096
    float* psum   = dinv + 4096;                       // 16
    float* h_x    = psum + 16;                         // N*HID
    float* hx     = h_x + (long)NN * HID;              // N*HID
    float* u_e    = hx + (long)NN * HID;               // NB*N*E_CH
    float* he     = u_e + (long)NB * NN * E_CH;        // NB*N*HID
    float* h_mu   = he + (long)NB * NN * HID;          // NB*N*OUT
    float* h_sg   = h_mu + (long)NB * NN * OUT_CH;     // NB*N*OUT

    float* omu = out + O_MU;
    float* osg = out + O_SG;

    hipMemsetAsync(degi, 0, NN * sizeof(int), stream);
    hipMemsetAsync(psum, 0, 16 * sizeof(float), stream);

    // CSR build
    k_deg<<<NE / 256, 256, 0, stream>>>(dst, degi);
    k_scan<<<1, 1024, 0, stream>>>(degi, rowptr, cursor, dinv);
    k_fill<<<NE / 256, 256, 0, stream>>>(src, dst, dinv, cursor, esrc, enorm);

    // x branch
    k_gemm_x<<<NN / 8, 256, 0, stream>>>(x, W1, h_x);
    k_agg_x<<<NN, 256, 0, stream>>>(h_x, rowptr, esrc, enorm, dinv, b1, hx, psum);

    // e branch: aggregate on 64 ch (all batches per wave), then GEMM (+bias +sumsq)
    k_agg_e<<<NN / 4, 256, 0, stream>>>(enoise, rowptr, esrc, enorm, dinv, u_e);
    k_gemm_e<<<NB * NN / 8, 256, 0, stream>>>(u_e, We, be, he, psum);

    // mu / sigma
    k_gemm_ms<<<dim3(NN / 16, NB), 256, 0, stream>>>(hx, he, Wmu, Wsg, h_mu, h_sg);
    k_agg16<<<NB * NN / 4, 256, 0, stream>>>(rowptr, esrc, enorm, dinv,
                                             h_mu, h_sg, bmu, bsg, omu, osg);

    // tail (z + rk + snr fused)
    k_z<<<(long)JJ * NN * OUT_CH / 256, 256, 0, stream>>>(omu, osg, eps,
                                                          out + O_Z, out + O_ZS, out + O_EPS,
                                                          rk_lgt, psum, out + O_RK, out + O_SNR);

    k_adj<<<dim3(NN / 128, NN / 128, JJ), 256, 0, stream>>>(out + O_Z, out);
}